// Round 3
// baseline (171.576 us; speedup 1.0000x reference)
//
#include <hip/hip_runtime.h>
#include <hip/hip_bf16.h>

typedef __attribute__((ext_vector_type(8))) short short8;
typedef __attribute__((ext_vector_type(4))) float f32x4;
typedef __attribute__((address_space(1))) const void gvoid_t;
typedef __attribute__((address_space(3))) void lvoid_t;

#define NB 4096   // B
#define DD 256    // D
#define TWOB 8192
#define NMACRO 1056u   // sum_{tr} (32 - tr/2) macro 128x256 tiles
#define GSUM_BLOCKS 16

__device__ __forceinline__ unsigned short f2bf(float f) {
  unsigned int u = __float_as_uint(f);
  u += 0x7fffu + ((u >> 16) & 1u);
  return (unsigned short)(u >> 16);
}
__device__ __forceinline__ float bf2f(unsigned short s) {
  return __uint_as_float(((unsigned int)s) << 16);
}

// ws layout (bytes):
//   [0, 32768)          den[8192] f32 (zeroed by norm blocks 0..31)
//   [65536, 4259840)    znb 8192x256 bf16
//   [4259840, 4276224)  vsum_part[16][4][256] f32
//   [4276224, 4276480)  cnt_part[16][4] int
//   [4276480, 4280576)  ppos[1024] f32
//
// R20: exact revert to R17 (108.3 us baseline: 2-buffer __syncthreads
// K-loop, den atomics, single-block tail). Single change:
// __launch_bounds__(256, 3) on den_kernel. 48 KB LDS and 116 VGPR already
// permit 3 blocks/CU (144 KB <= 160 KB, 116 <= 170); the previous (256,2)
// bound let the allocator settle at 2. 12 waves/CU overlaps the per-K-step
// barrier drain and the per-tile epilogue across 3 blocks.
// R18 post-mortem: fence-storm + 72KB LDS regression (den 73.8us).
// R19 post-mortem: atomics were NOT the bottleneck (removing them cost
// +8.5us net). Pipes: MFMA 20.5K cyc/CU vs LDS 19K cyc/CU near-parity;
// occupancy is the remaining lever inside this structure.

// ---------------- kernel A: zero den; normalize -> znb bf16; ppos ---------
__global__ __launch_bounds__(256) void norm_kernel(const float* __restrict__ zi,
                                                   const float* __restrict__ zj,
                                                   float* __restrict__ wsf,
                                                   float* __restrict__ ppos,
                                                   unsigned short* __restrict__ znb) {
  __shared__ float sred[4];
  if (blockIdx.x < 32) wsf[blockIdx.x * 256 + threadIdx.x] = 0.f;
  const int lane = threadIdx.x & 63, wave = threadIdx.x >> 6;
  const int i = blockIdx.x * 4 + wave;

  float4 a = ((const float4*)(zi + (size_t)i * DD))[lane];
  float4 b = ((const float4*)(zj + (size_t)i * DD))[lane];
  float sa = a.x * a.x + a.y * a.y + a.z * a.z + a.w * a.w;
  float sb = b.x * b.x + b.y * b.y + b.z * b.z + b.w * b.w;
  float sab = a.x * b.x + a.y * b.y + a.z * b.z + a.w * b.w;
#pragma unroll
  for (int m = 32; m >= 1; m >>= 1) {
    sa += __shfl_xor(sa, m);
    sb += __shfl_xor(sb, m);
    sab += __shfl_xor(sab, m);
  }
  float ra = 1.0f / fmaxf(sqrtf(sa), 1e-8f);
  float rb = 1.0f / fmaxf(sqrtf(sb), 1e-8f);
  ushort4 oa, ob;
  oa.x = f2bf(a.x * ra); oa.y = f2bf(a.y * ra); oa.z = f2bf(a.z * ra); oa.w = f2bf(a.w * ra);
  ob.x = f2bf(b.x * rb); ob.y = f2bf(b.y * rb); ob.z = f2bf(b.z * rb); ob.w = f2bf(b.w * rb);
  ((ushort4*)(znb + (size_t)i * DD))[lane] = oa;
  ((ushort4*)(znb + (size_t)(i + NB) * DD))[lane] = ob;

  if (lane == 0) sred[wave] = sab * ra * rb;  // exact fp32 pos (row i)
  __syncthreads();
  if (threadIdx.x == 0)
    ppos[blockIdx.x] = sred[0] + sred[1] + sred[2] + sred[3];
}

// ---------------- kernel B: gsum + 128x256 macro den tiles ----------------
__global__ __launch_bounds__(256, 3) void den_kernel(const int* __restrict__ sf,
                                                     float* __restrict__ wsf,
                                                     const unsigned short* __restrict__ znb,
                                                     float* __restrict__ vsum_part,
                                                     int* __restrict__ cnt_part) {
  __shared__ __align__(16) unsigned short As[2][4096];  // 16 KB (A: 128 rows)
  __shared__ __align__(16) unsigned short Bs[2][8192];  // 32 KB (B: 256 cols)

  float* den = wsf;

  const int tid = threadIdx.x;
  const int lane = tid & 63, wave = tid >> 6;
  const unsigned t_lin = blockIdx.y * 64u + blockIdx.x;

  if (t_lin < GSUM_BLOCKS) {
    // ---- gsum: 256 rows, LDS reduce, plain stores ------------------------
    const int b = (int)t_lin;
    const int r0 = b * 256;
    float acc[4][4];
#pragma unroll
    for (int q = 0; q < 4; ++q)
#pragma unroll
      for (int e = 0; e < 4; ++e) acc[q][e] = 0.f;
    int cnt[4] = {0, 0, 0, 0};
    const int rw = r0 + wave * 64;
    for (int k = 0; k < 64; ++k) {
      int row = rw + k;
      int g = sf[row];
      ushort4 v = ((const ushort4*)(znb + (size_t)row * DD))[lane];
      float f0 = bf2f(v.x), f1 = bf2f(v.y), f2 = bf2f(v.z), f3 = bf2f(v.w);
#pragma unroll
      for (int q = 0; q < 4; ++q) {
        bool sel = (g == q);
        acc[q][0] += sel ? f0 : 0.f;
        acc[q][1] += sel ? f1 : 0.f;
        acc[q][2] += sel ? f2 : 0.f;
        acc[q][3] += sel ? f3 : 0.f;
        cnt[q] += sel ? 1 : 0;
      }
    }
    float4* lsd = (float4*)&As[0][0];
    int* lcnt = (int*)&Bs[0][0];
#pragma unroll
    for (int q = 0; q < 4; ++q) {
      float4 t;
      t.x = acc[q][0]; t.y = acc[q][1]; t.z = acc[q][2]; t.w = acc[q][3];
      lsd[(wave * 4 + q) * 64 + lane] = t;
    }
    if (lane == 0) {
#pragma unroll
      for (int q = 0; q < 4; ++q) lcnt[wave * 4 + q] = cnt[q];
    }
    __syncthreads();
    {
      int g = tid >> 6, l = tid & 63;
      float4 s0 = lsd[(0 + g) * 64 + l];
      float4 s1 = lsd[(4 + g) * 64 + l];
      float4 s2 = lsd[(8 + g) * 64 + l];
      float4 s3 = lsd[(12 + g) * 64 + l];
      float4 s;
      s.x = s0.x + s1.x + s2.x + s3.x;
      s.y = s0.y + s1.y + s2.y + s3.y;
      s.z = s0.z + s1.z + s2.z + s3.z;
      s.w = s0.w + s1.w + s2.w + s3.w;
      ((float4*)(vsum_part + (size_t)(b * 4 + g) * 256))[l] = s;
      if (tid < 4)
        cnt_part[b * 4 + tid] = lcnt[tid] + lcnt[4 + tid] + lcnt[8 + tid] + lcnt[12 + tid];
    }
    return;
  }
  if (t_lin >= NMACRO + GSUM_BLOCKS) return;  // spares

  // ---- one 128x256 macro tile ------------------------------------------
  unsigned t = t_lin - GSUM_BLOCKS;
  unsigned tr = 0;
  while (t >= 32u - (tr >> 1)) { t -= 32u - (tr >> 1); ++tr; }
  unsigned c = (tr >> 1) + t;
  const size_t rowbase = (size_t)tr * 128;
  const size_t colbase = (size_t)c * 256;
  const int tc0 = (int)(2 * c), tc1 = (int)(2 * c + 1);

  const int u = lane >> 3;
  const int cp = (lane & 7) ^ u;
  const int ri = 2 * u + (cp >> 2);
  const int kelem = (cp & 3) * 8;
  const int slot = ((((lane & 1) << 2) | (lane >> 4)) ^ ((lane >> 1) & 7));
  const int fragoff = ((lane & 15) >> 1) * 128 + slot * 16;
  const int wrow = wave & 1, wcol = wave >> 1;

  // wave-uniform symmetry flags for this wave's 128-col half
  const int tch = wcol ? tc1 : tc0;
  const float fr = (tch >= (int)tr) ? 1.f : 0.f;  // include in row sums
  const float fc = (tch > (int)tr) ? 1.f : 0.f;   // include in col sums

  f32x4 zero = {0.f, 0.f, 0.f, 0.f};
  f32x4 acc[4][8];
#pragma unroll
  for (int i = 0; i < 4; ++i)
#pragma unroll
    for (int j = 0; j < 8; ++j) acc[i][j] = zero;

  auto stage = [&](int kt, int buf) {
#pragma unroll
    for (int j = 0; j < 2; ++j) {
      int is = wave * 2 + j;
      const unsigned short* gpa = znb + (rowbase + is * 16 + ri) * DD + kt * 32 + kelem;
      __builtin_amdgcn_global_load_lds((gvoid_t*)gpa, (lvoid_t*)&As[buf][is * 512], 16, 0, 0);
    }
#pragma unroll
    for (int j = 0; j < 4; ++j) {
      int is = wave * 4 + j;
      const unsigned short* gpb = znb + (colbase + is * 16 + ri) * DD + kt * 32 + kelem;
      __builtin_amdgcn_global_load_lds((gvoid_t*)gpb, (lvoid_t*)&Bs[buf][is * 512], 16, 0, 0);
    }
  };

  stage(0, 0);
  __syncthreads();
#pragma unroll
  for (int kt = 0; kt < 8; ++kt) {
    if (kt < 7) stage(kt + 1, (kt + 1) & 1);
    const int buf = kt & 1;
    short8 af[4], bfr[8];
#pragma unroll
    for (int mi = 0; mi < 4; ++mi)
      af[mi] = *(const short8*)((const char*)&As[0][0] + buf * 8192 + wrow * 4096 + mi * 1024 + fragoff);
#pragma unroll
    for (int ni = 0; ni < 8; ++ni)
      bfr[ni] = *(const short8*)((const char*)&Bs[0][0] + buf * 16384 + wcol * 8192 + ni * 1024 + fragoff);
#pragma unroll
    for (int mi = 0; mi < 4; ++mi)
#pragma unroll
      for (int ni = 0; ni < 8; ++ni)
        acc[mi][ni] = __builtin_amdgcn_mfma_f32_16x16x32_bf16(af[mi], bfr[ni], acc[mi][ni], 0, 0, 0);
    __syncthreads();
  }

  // epilogue: e = exp(2S); row/col sums with wave-uniform fr/fc; combine in
  // LDS; atomics; end at s_endpgm. C layout: col=lane&15, row=(lane>>4)*4+reg.
  float rsum[4][4];
  float csum[8];
#pragma unroll
  for (int mi = 0; mi < 4; ++mi)
#pragma unroll
    for (int r = 0; r < 4; ++r) rsum[mi][r] = 0.f;
#pragma unroll
  for (int ni = 0; ni < 8; ++ni) csum[ni] = 0.f;
#pragma unroll
  for (int mi = 0; mi < 4; ++mi)
#pragma unroll
    for (int ni = 0; ni < 8; ++ni)
#pragma unroll
      for (int r = 0; r < 4; ++r) {
        float e = __expf(2.0f * acc[mi][ni][r]);
        rsum[mi][r] += e;
        csum[ni] += e;
      }
#pragma unroll
  for (int m = 1; m < 16; m <<= 1)
#pragma unroll
    for (int mi = 0; mi < 4; ++mi)
#pragma unroll
      for (int r = 0; r < 4; ++r) rsum[mi][r] += __shfl_xor(rsum[mi][r], m);
#pragma unroll
  for (int m = 16; m < 64; m <<= 1)
#pragma unroll
    for (int ni = 0; ni < 8; ++ni) csum[ni] += __shfl_xor(csum[ni], m);

  float* Lr = (float*)&As[0][0];  // [2][128] indexed by wcol
  float* Lc = Lr + 256;           // [2][256] indexed by wrow
  if ((lane & 15) == 0) {
    int h = lane >> 4;
#pragma unroll
    for (int mi = 0; mi < 4; ++mi)
#pragma unroll
      for (int r = 0; r < 4; ++r)
        Lr[wcol * 128 + wrow * 64 + mi * 16 + h * 4 + r] = rsum[mi][r] * fr;
  }
  if (lane < 16) {
#pragma unroll
    for (int ni = 0; ni < 8; ++ni)
      Lc[wrow * 256 + wcol * 128 + ni * 16 + lane] = csum[ni] * fc;
  }
  __syncthreads();
  // 256 threads each take one column; threads 0..127 also a row.
  if (tid < 128) {
    unsafeAtomicAdd(&den[rowbase + tid], Lr[tid] + Lr[128 + tid]);
  }
  {
    float v = Lc[tid] + Lc[256 + tid];
    if (v != 0.f) unsafeAtomicAdd(&den[colbase + tid], v);
  }
}

// ---------------- kernel C: tail (1 block) --------------------------------
__global__ __launch_bounds__(256) void tail_kernel(const float* __restrict__ wsf,
                                                   const float* __restrict__ vsum_part,
                                                   const int* __restrict__ cnt_part,
                                                   const float* __restrict__ ppos,
                                                   float* __restrict__ out) {
  __shared__ float sred[32];
  const float* den = wsf;
  const int tid = threadIdx.x;
  const int lane = tid & 63, wave = tid >> 6;

  const float e2 = __expf(2.0f);
  float ls = 0.f;
  for (int i = tid; i < TWOB; i += 256) ls += __logf(den[i] - e2);
#pragma unroll
  for (int m = 32; m >= 1; m >>= 1) ls += __shfl_xor(ls, m);
  if (lane == 0) sred[wave] = ls;

  float pp = 0.f;
#pragma unroll
  for (int k = 0; k < 4; ++k) pp += ppos[k * 256 + tid];
#pragma unroll
  for (int m = 32; m >= 1; m >>= 1) pp += __shfl_xor(pp, m);
  if (lane == 0) sred[4 + wave] = pp;

  float gp[4];
#pragma unroll
  for (int g = 0; g < 4; ++g) {
    float v = 0.f;
#pragma unroll
    for (int b = 0; b < 16; ++b) v += vsum_part[(size_t)(b * 4 + g) * 256 + tid];
    gp[g] = v * v;
#pragma unroll
    for (int m = 32; m >= 1; m >>= 1) gp[g] += __shfl_xor(gp[g], m);
  }
  if (lane == 0) {
#pragma unroll
    for (int g = 0; g < 4; ++g) sred[8 + wave * 4 + g] = gp[g];
  }
  __syncthreads();
  if (tid == 0) {
    float lsum = sred[0] + sred[1] + sred[2] + sred[3];
    float psum = sred[4] + sred[5] + sred[6] + sred[7];
    float contrastive = (lsum - 4.0f * psum) / (float)TWOB;
    float fsum = 0.f;
    int uniq = 0;
#pragma unroll
    for (int q = 0; q < 4; ++q) {
      int ci = 0;
#pragma unroll
      for (int b = 0; b < 16; ++b) ci += cnt_part[b * 4 + q];
      float gsq = sred[8 + q] + sred[12 + q] + sred[16 + q] + sred[20 + q];
      float c = (float)ci;
      if (ci > 0) uniq++;
      if (ci > 1) fsum += gsq / (c * (c - 1.0f));
    }
    out[0] = contrastive + 0.1f * (fsum / (uniq > 0 ? (float)uniq : 1.0f));
  }
}

extern "C" void kernel_launch(void* const* d_in, const int* in_sizes, int n_in,
                              void* d_out, int out_size, void* d_ws, size_t ws_size,
                              hipStream_t stream) {
  const float* zi = (const float*)d_in[0];
  const float* zj = (const float*)d_in[1];
  const int* sf = (const int*)d_in[2];
  float* out = (float*)d_out;
  char* ws = (char*)d_ws;
  float* wsf = (float*)ws;                              // den
  unsigned short* znb = (unsigned short*)(ws + 65536);  // 8192x256 bf16 (4MB)
  float* vsum_part = (float*)(ws + 4259840);            // 16x4x256 f32
  int* cnt_part = (int*)(ws + 4276224);                 // 16x4 int
  float* ppos = (float*)(ws + 4276480);                 // 1024 f32

  hipLaunchKernelGGL(norm_kernel, dim3(1024), dim3(256), 0, stream, zi, zj, wsf, ppos, znb);
  hipLaunchKernelGGL(den_kernel, dim3(64, 17), dim3(256), 0, stream,
                     sf, wsf, znb, vsum_part, cnt_part);
  hipLaunchKernelGGL(tail_kernel, dim3(1), dim3(256), 0, stream,
                     wsf, vsum_part, cnt_part, ppos, out);
}

// Round 4
// 109.538 us; speedup vs baseline: 1.5664x; 1.5664x over previous
//
#include <hip/hip_runtime.h>
#include <hip/hip_bf16.h>

typedef __attribute__((ext_vector_type(8))) short short8;
typedef __attribute__((ext_vector_type(4))) float f32x4;
typedef __attribute__((address_space(1))) const void gvoid_t;
typedef __attribute__((address_space(3))) void lvoid_t;

#define NB 4096   // B
#define DD 256    // D
#define TWOB 8192
#define NMACRO 1056u   // sum_{tr} (32 - tr/2) macro 128x256 tiles
#define GSUM_BLOCKS 16

__device__ __forceinline__ unsigned short f2bf(float f) {
  unsigned int u = __float_as_uint(f);
  u += 0x7fffu + ((u >> 16) & 1u);
  return (unsigned short)(u >> 16);
}
__device__ __forceinline__ float bf2f(unsigned short s) {
  return __uint_as_float(((unsigned int)s) << 16);
}

// ws layout (bytes):
//   [0, 32768)          den[8192] f32 (zeroed by norm blocks 0..31)
//   [65536, 4259840)    znb 8192x256 bf16
//   [4259840, 4276224)  vsum_part[16][4][256] f32
//   [4276224, 4276480)  cnt_part[16][4] int
//   [4276480, 4280576)  ppos[1024] f32
//
// R21: occupancy via smaller per-wave accumulator. R20 post-mortem: the
// unified VGPR+AGPR budget is ~244/wave for a 64x128 per-wave tile (128-reg
// acc) -> hard 2 waves/SIMD; forcing 3 blocks spilled acc to scratch
// (VGPR 116->84, WRITE 196 MB, den 100us). This round: SAME 128x256 block
// tile, SAME LDS byte layout and K-loop, but 8 waves x (64x64) per wave:
// acc = 64 regs, ~110-125 total -> __launch_bounds__(512,4) = 4 waves/SIMD,
// 16 waves/CU (2x R17). LDS reads +33% (still under pipe floor); we are
// latency-bound at 2 waves/SIMD per R17..R20 evidence.

// ---------------- kernel A: zero den; normalize -> znb bf16; ppos ---------
__global__ __launch_bounds__(256) void norm_kernel(const float* __restrict__ zi,
                                                   const float* __restrict__ zj,
                                                   float* __restrict__ wsf,
                                                   float* __restrict__ ppos,
                                                   unsigned short* __restrict__ znb) {
  __shared__ float sred[4];
  if (blockIdx.x < 32) wsf[blockIdx.x * 256 + threadIdx.x] = 0.f;
  const int lane = threadIdx.x & 63, wave = threadIdx.x >> 6;
  const int i = blockIdx.x * 4 + wave;

  float4 a = ((const float4*)(zi + (size_t)i * DD))[lane];
  float4 b = ((const float4*)(zj + (size_t)i * DD))[lane];
  float sa = a.x * a.x + a.y * a.y + a.z * a.z + a.w * a.w;
  float sb = b.x * b.x + b.y * b.y + b.z * b.z + b.w * b.w;
  float sab = a.x * b.x + a.y * b.y + a.z * b.z + a.w * b.w;
#pragma unroll
  for (int m = 32; m >= 1; m >>= 1) {
    sa += __shfl_xor(sa, m);
    sb += __shfl_xor(sb, m);
    sab += __shfl_xor(sab, m);
  }
  float ra = 1.0f / fmaxf(sqrtf(sa), 1e-8f);
  float rb = 1.0f / fmaxf(sqrtf(sb), 1e-8f);
  ushort4 oa, ob;
  oa.x = f2bf(a.x * ra); oa.y = f2bf(a.y * ra); oa.z = f2bf(a.z * ra); oa.w = f2bf(a.w * ra);
  ob.x = f2bf(b.x * rb); ob.y = f2bf(b.y * rb); ob.z = f2bf(b.z * rb); ob.w = f2bf(b.w * rb);
  ((ushort4*)(znb + (size_t)i * DD))[lane] = oa;
  ((ushort4*)(znb + (size_t)(i + NB) * DD))[lane] = ob;

  if (lane == 0) sred[wave] = sab * ra * rb;  // exact fp32 pos (row i)
  __syncthreads();
  if (threadIdx.x == 0)
    ppos[blockIdx.x] = sred[0] + sred[1] + sred[2] + sred[3];
}

// ---------------- kernel B: gsum + 128x256 macro den tiles (8 waves) ------
__global__ __launch_bounds__(512, 4) void den_kernel(const int* __restrict__ sf,
                                                     float* __restrict__ wsf,
                                                     const unsigned short* __restrict__ znb,
                                                     float* __restrict__ vsum_part,
                                                     int* __restrict__ cnt_part) {
  __shared__ __align__(16) unsigned short As[2][4096];  // 16 KB (A: 128 rows)
  __shared__ __align__(16) unsigned short Bs[2][8192];  // 32 KB (B: 256 cols)

  float* den = wsf;

  const int tid = threadIdx.x;
  const int lane = tid & 63, wave = tid >> 6;  // wave 0..7
  const unsigned t_lin = blockIdx.y * 64u + blockIdx.x;

  if (t_lin < GSUM_BLOCKS) {
    // ---- gsum: 256 rows over 8 waves (32 rows each), LDS reduce ----------
    const int b = (int)t_lin;
    const int r0 = b * 256;
    float acc[4][4];
#pragma unroll
    for (int q = 0; q < 4; ++q)
#pragma unroll
      for (int e = 0; e < 4; ++e) acc[q][e] = 0.f;
    int cnt[4] = {0, 0, 0, 0};
    const int rw = r0 + wave * 32;
    for (int k = 0; k < 32; ++k) {
      int row = rw + k;
      int g = sf[row];
      ushort4 v = ((const ushort4*)(znb + (size_t)row * DD))[lane];
      float f0 = bf2f(v.x), f1 = bf2f(v.y), f2 = bf2f(v.z), f3 = bf2f(v.w);
#pragma unroll
      for (int q = 0; q < 4; ++q) {
        bool sel = (g == q);
        acc[q][0] += sel ? f0 : 0.f;
        acc[q][1] += sel ? f1 : 0.f;
        acc[q][2] += sel ? f2 : 0.f;
        acc[q][3] += sel ? f3 : 0.f;
        cnt[q] += sel ? 1 : 0;
      }
    }
    float4* lsd = (float4*)&Bs[0][0];  // 32 x 64 float4 = 32 KB
    int* lcnt = (int*)&As[0][0];       // 32 ints
#pragma unroll
    for (int q = 0; q < 4; ++q) {
      float4 t;
      t.x = acc[q][0]; t.y = acc[q][1]; t.z = acc[q][2]; t.w = acc[q][3];
      lsd[(wave * 4 + q) * 64 + lane] = t;
    }
    if (lane == 0) {
#pragma unroll
      for (int q = 0; q < 4; ++q) lcnt[wave * 4 + q] = cnt[q];
    }
    __syncthreads();
    if (tid < 256) {
      int g = tid >> 6, l = tid & 63;
      float4 s = {0.f, 0.f, 0.f, 0.f};
#pragma unroll
      for (int w = 0; w < 8; ++w) {
        float4 sv = lsd[(w * 4 + g) * 64 + l];
        s.x += sv.x; s.y += sv.y; s.z += sv.z; s.w += sv.w;
      }
      ((float4*)(vsum_part + (size_t)(b * 4 + g) * 256))[l] = s;
      if (tid < 4) {
        int ci = 0;
#pragma unroll
        for (int w = 0; w < 8; ++w) ci += lcnt[w * 4 + tid];
        cnt_part[b * 4 + tid] = ci;
      }
    }
    return;
  }
  if (t_lin >= NMACRO + GSUM_BLOCKS) return;  // spares

  // ---- one 128x256 macro tile, 8 waves x (64x64) -------------------------
  unsigned t = t_lin - GSUM_BLOCKS;
  unsigned tr = 0;
  while (t >= 32u - (tr >> 1)) { t -= 32u - (tr >> 1); ++tr; }
  unsigned c = (tr >> 1) + t;
  const size_t rowbase = (size_t)tr * 128;
  const size_t colbase = (size_t)c * 256;

  const int u = lane >> 3;
  const int cp = (lane & 7) ^ u;
  const int ri = 2 * u + (cp >> 2);
  const int kelem = (cp & 3) * 8;
  const int slot = ((((lane & 1) << 2) | (lane >> 4)) ^ ((lane >> 1) & 7));
  const int fragoff = ((lane & 15) >> 1) * 128 + slot * 16;
  const int wrow = wave & 1;       // 64-row half
  const int wcol = wave >> 1;      // 64-col quarter (0..3)

  // wave-uniform symmetry flags at 128x128 sub-block granularity
  const int tch = (int)(2 * c) + (wcol >> 1);     // this wave's 128-col half
  const float fr = (tch >= (int)tr) ? 1.f : 0.f;  // include in row sums
  const float fc = (tch > (int)tr) ? 1.f : 0.f;   // include in col sums

  f32x4 zero = {0.f, 0.f, 0.f, 0.f};
  f32x4 acc[4][4];
#pragma unroll
  for (int i = 0; i < 4; ++i)
#pragma unroll
    for (int j = 0; j < 4; ++j) acc[i][j] = zero;

  // staging bases: each wave issues 1 A chunk + 2 B chunks (16-row units);
  // byte layout in LDS identical to the verified 4-wave version.
  const unsigned short* gA = znb + (rowbase + wave * 16 + ri) * DD + kelem;
  const unsigned short* gB0 = znb + (colbase + (2 * wave) * 16 + ri) * DD + kelem;
  const unsigned short* gB1 = gB0 + 16 * DD;

  auto stage = [&](int kt, int buf) {
    __builtin_amdgcn_global_load_lds((gvoid_t*)(gA + kt * 32), (lvoid_t*)&As[buf][wave * 512], 16, 0, 0);
    __builtin_amdgcn_global_load_lds((gvoid_t*)(gB0 + kt * 32), (lvoid_t*)&Bs[buf][(2 * wave) * 512], 16, 0, 0);
    __builtin_amdgcn_global_load_lds((gvoid_t*)(gB1 + kt * 32), (lvoid_t*)&Bs[buf][(2 * wave + 1) * 512], 16, 0, 0);
  };

  stage(0, 0);
  __syncthreads();
#pragma unroll
  for (int kt = 0; kt < 8; ++kt) {
    if (kt < 7) stage(kt + 1, (kt + 1) & 1);
    const int buf = kt & 1;
    short8 af[4], bfr[4];
#pragma unroll
    for (int mi = 0; mi < 4; ++mi)
      af[mi] = *(const short8*)((const char*)&As[0][0] + buf * 8192 + (wrow * 4 + mi) * 1024 + fragoff);
#pragma unroll
    for (int ni = 0; ni < 4; ++ni)
      bfr[ni] = *(const short8*)((const char*)&Bs[0][0] + buf * 16384 + (wcol * 4 + ni) * 1024 + fragoff);
#pragma unroll
    for (int mi = 0; mi < 4; ++mi)
#pragma unroll
      for (int ni = 0; ni < 4; ++ni)
        acc[mi][ni] = __builtin_amdgcn_mfma_f32_16x16x32_bf16(af[mi], bfr[ni], acc[mi][ni], 0, 0, 0);
    __syncthreads();
  }

  // epilogue: e = exp(2S); row/col sums; combine in LDS; atomics.
  // C layout: col=lane&15, row=(lane>>4)*4+reg.
  float rsum[4][4];
  float csum[4];
#pragma unroll
  for (int mi = 0; mi < 4; ++mi)
#pragma unroll
    for (int r = 0; r < 4; ++r) rsum[mi][r] = 0.f;
#pragma unroll
  for (int ni = 0; ni < 4; ++ni) csum[ni] = 0.f;
#pragma unroll
  for (int mi = 0; mi < 4; ++mi)
#pragma unroll
    for (int ni = 0; ni < 4; ++ni)
#pragma unroll
      for (int r = 0; r < 4; ++r) {
        float e = __expf(2.0f * acc[mi][ni][r]);
        rsum[mi][r] += e;
        csum[ni] += e;
      }
#pragma unroll
  for (int m = 1; m < 16; m <<= 1)
#pragma unroll
    for (int mi = 0; mi < 4; ++mi)
#pragma unroll
      for (int r = 0; r < 4; ++r) rsum[mi][r] += __shfl_xor(rsum[mi][r], m);
#pragma unroll
  for (int m = 16; m < 64; m <<= 1)
#pragma unroll
    for (int ni = 0; ni < 4; ++ni) csum[ni] += __shfl_xor(csum[ni], m);

  float* Lr = (float*)&As[0][0];  // [4][128] indexed by wcol (2 KB)
  float* Lc = Lr + 512;           // [2][256] indexed by wrow (2 KB)
  if ((lane & 15) == 0) {
    int h = lane >> 4;
#pragma unroll
    for (int mi = 0; mi < 4; ++mi)
#pragma unroll
      for (int r = 0; r < 4; ++r)
        Lr[wcol * 128 + wrow * 64 + mi * 16 + h * 4 + r] = rsum[mi][r] * fr;
  }
  if (lane < 16) {
#pragma unroll
    for (int ni = 0; ni < 4; ++ni)
      Lc[wrow * 256 + wcol * 64 + ni * 16 + lane] = csum[ni] * fc;
  }
  __syncthreads();
  if (tid < 256) {
    float v = Lc[tid] + Lc[256 + tid];
    if (v != 0.f) unsafeAtomicAdd(&den[colbase + tid], v);
  } else if (tid < 384) {
    int r = tid - 256;
    unsafeAtomicAdd(&den[rowbase + r], Lr[r] + Lr[128 + r] + Lr[256 + r] + Lr[384 + r]);
  }
}

// ---------------- kernel C: tail (1 block) --------------------------------
__global__ __launch_bounds__(256) void tail_kernel(const float* __restrict__ wsf,
                                                   const float* __restrict__ vsum_part,
                                                   const int* __restrict__ cnt_part,
                                                   const float* __restrict__ ppos,
                                                   float* __restrict__ out) {
  __shared__ float sred[32];
  const float* den = wsf;
  const int tid = threadIdx.x;
  const int lane = tid & 63, wave = tid >> 6;

  const float e2 = __expf(2.0f);
  float ls = 0.f;
  for (int i = tid; i < TWOB; i += 256) ls += __logf(den[i] - e2);
#pragma unroll
  for (int m = 32; m >= 1; m >>= 1) ls += __shfl_xor(ls, m);
  if (lane == 0) sred[wave] = ls;

  float pp = 0.f;
#pragma unroll
  for (int k = 0; k < 4; ++k) pp += ppos[k * 256 + tid];
#pragma unroll
  for (int m = 32; m >= 1; m >>= 1) pp += __shfl_xor(pp, m);
  if (lane == 0) sred[4 + wave] = pp;

  float gp[4];
#pragma unroll
  for (int g = 0; g < 4; ++g) {
    float v = 0.f;
#pragma unroll
    for (int b = 0; b < 16; ++b) v += vsum_part[(size_t)(b * 4 + g) * 256 + tid];
    gp[g] = v * v;
#pragma unroll
    for (int m = 32; m >= 1; m >>= 1) gp[g] += __shfl_xor(gp[g], m);
  }
  if (lane == 0) {
#pragma unroll
    for (int g = 0; g < 4; ++g) sred[8 + wave * 4 + g] = gp[g];
  }
  __syncthreads();
  if (tid == 0) {
    float lsum = sred[0] + sred[1] + sred[2] + sred[3];
    float psum = sred[4] + sred[5] + sred[6] + sred[7];
    float contrastive = (lsum - 4.0f * psum) / (float)TWOB;
    float fsum = 0.f;
    int uniq = 0;
#pragma unroll
    for (int q = 0; q < 4; ++q) {
      int ci = 0;
#pragma unroll
      for (int b = 0; b < 16; ++b) ci += cnt_part[b * 4 + q];
      float gsq = sred[8 + q] + sred[12 + q] + sred[16 + q] + sred[20 + q];
      float c = (float)ci;
      if (ci > 0) uniq++;
      if (ci > 1) fsum += gsq / (c * (c - 1.0f));
    }
    out[0] = contrastive + 0.1f * (fsum / (uniq > 0 ? (float)uniq : 1.0f));
  }
}

extern "C" void kernel_launch(void* const* d_in, const int* in_sizes, int n_in,
                              void* d_out, int out_size, void* d_ws, size_t ws_size,
                              hipStream_t stream) {
  const float* zi = (const float*)d_in[0];
  const float* zj = (const float*)d_in[1];
  const int* sf = (const int*)d_in[2];
  float* out = (float*)d_out;
  char* ws = (char*)d_ws;
  float* wsf = (float*)ws;                              // den
  unsigned short* znb = (unsigned short*)(ws + 65536);  // 8192x256 bf16 (4MB)
  float* vsum_part = (float*)(ws + 4259840);            // 16x4x256 f32
  int* cnt_part = (int*)(ws + 4276224);                 // 16x4 int
  float* ppos = (float*)(ws + 4276480);                 // 1024 f32

  hipLaunchKernelGGL(norm_kernel, dim3(1024), dim3(256), 0, stream, zi, zj, wsf, ppos, znb);
  hipLaunchKernelGGL(den_kernel, dim3(64, 17), dim3(512), 0, stream,
                     sf, wsf, znb, vsum_part, cnt_part);
  hipLaunchKernelGGL(tail_kernel, dim3(1), dim3(256), 0, stream,
                     wsf, vsum_part, cnt_part, ppos, out);
}

// Round 5
// 96.652 us; speedup vs baseline: 1.7752x; 1.1333x over previous
//
#include <hip/hip_runtime.h>
#include <hip/hip_bf16.h>

typedef __attribute__((ext_vector_type(8))) short short8;
typedef __attribute__((ext_vector_type(4))) float f32x4;
typedef __attribute__((address_space(1))) const void gvoid_t;
typedef __attribute__((address_space(3))) void lvoid_t;

#define NB 4096   // B
#define DD 256    // D
#define TWOB 8192
#define NMACRO 1056u   // sum_{tr} (32 - tr/2) macro 128x256 tiles
#define GSUM_BLOCKS 16
#define NPART 1072u    // gsum + macro blocks (8 x 134 exactly)

__device__ __forceinline__ unsigned short f2bf(float f) {
  unsigned int u = __float_as_uint(f);
  u += 0x7fffu + ((u >> 16) & 1u);
  return (unsigned short)(u >> 16);
}
__device__ __forceinline__ float bf2f(unsigned short s) {
  return __uint_as_float(((unsigned int)s) << 16);
}

// ws layout (bytes):
//   [0, 32768)          den[8192] f32 (zeroed by norm blocks 0..31)
//   [65536, 4259840)    znb 8192x256 bf16
//   [4259840, 4276224)  vsum_part[16][4][256] f32
//   [4276224, 4276480)  cnt_part[16][4] int
//   [4276480, 4280576)  ppos[1024] f32
//
// R22: isolate T4 on the R21 geometry. R20: forcing 3 blocks spilled acc
// (VGPR budget ~244/wave at 64x128 tile). R21: 2x occupancy (16 waves/CU)
// was NEUTRAL -> stall is taken at the per-K-step __syncthreads vmcnt(0)
// drain by ALL waves together (per-step compute ~350cyc/SIMD < load RTT
// ~600-900cyc). This round: 3 LDS buffers (72KB, still 2 blocks/CU),
// prefetch distance 2, s_waitcnt vmcnt(3) + ONE raw s_barrier per K-step
// (no vmcnt(0) in loop body), empty asm memory-fence after the barrier so
// hipcc can't hoist the next stage() above it. No device fences, no
// fused tail (R18's confounds). Plus: bijective XCD swizzle of the 1072
// participants (8x134), and tail widened to 1024 threads.

// ---------------- kernel A: zero den; normalize -> znb bf16; ppos ---------
__global__ __launch_bounds__(256) void norm_kernel(const float* __restrict__ zi,
                                                   const float* __restrict__ zj,
                                                   float* __restrict__ wsf,
                                                   float* __restrict__ ppos,
                                                   unsigned short* __restrict__ znb) {
  __shared__ float sred[4];
  if (blockIdx.x < 32) wsf[blockIdx.x * 256 + threadIdx.x] = 0.f;
  const int lane = threadIdx.x & 63, wave = threadIdx.x >> 6;
  const int i = blockIdx.x * 4 + wave;

  float4 a = ((const float4*)(zi + (size_t)i * DD))[lane];
  float4 b = ((const float4*)(zj + (size_t)i * DD))[lane];
  float sa = a.x * a.x + a.y * a.y + a.z * a.z + a.w * a.w;
  float sb = b.x * b.x + b.y * b.y + b.z * b.z + b.w * b.w;
  float sab = a.x * b.x + a.y * b.y + a.z * b.z + a.w * b.w;
#pragma unroll
  for (int m = 32; m >= 1; m >>= 1) {
    sa += __shfl_xor(sa, m);
    sb += __shfl_xor(sb, m);
    sab += __shfl_xor(sab, m);
  }
  float ra = 1.0f / fmaxf(sqrtf(sa), 1e-8f);
  float rb = 1.0f / fmaxf(sqrtf(sb), 1e-8f);
  ushort4 oa, ob;
  oa.x = f2bf(a.x * ra); oa.y = f2bf(a.y * ra); oa.z = f2bf(a.z * ra); oa.w = f2bf(a.w * ra);
  ob.x = f2bf(b.x * rb); ob.y = f2bf(b.y * rb); ob.z = f2bf(b.z * rb); ob.w = f2bf(b.w * rb);
  ((ushort4*)(znb + (size_t)i * DD))[lane] = oa;
  ((ushort4*)(znb + (size_t)(i + NB) * DD))[lane] = ob;

  if (lane == 0) sred[wave] = sab * ra * rb;  // exact fp32 pos (row i)
  __syncthreads();
  if (threadIdx.x == 0)
    ppos[blockIdx.x] = sred[0] + sred[1] + sred[2] + sred[3];
}

// ---------------- kernel B: gsum + 128x256 macro den tiles (8 waves) ------
__global__ __launch_bounds__(512, 4) void den_kernel(const int* __restrict__ sf,
                                                     float* __restrict__ wsf,
                                                     const unsigned short* __restrict__ znb,
                                                     float* __restrict__ vsum_part,
                                                     int* __restrict__ cnt_part) {
  __shared__ __align__(16) unsigned short As[3][4096];  // 24 KB (A: 128 rows, 3 bufs)
  __shared__ __align__(16) unsigned short Bs[3][8192];  // 48 KB (B: 256 cols, 3 bufs)

  float* den = wsf;

  const int tid = threadIdx.x;
  const int lane = tid & 63, wave = tid >> 6;  // wave 0..7
  const unsigned t_raw = blockIdx.y * 64u + blockIdx.x;
  if (t_raw >= NPART) return;  // spares
  // bijective XCD swizzle: 1072 = 8 x 134; raw id r*... -> XCD (t_raw&7)
  // gets contiguous tile range [x*134, (x+1)*134).
  const unsigned t_lin = (t_raw & 7u) * 134u + (t_raw >> 3);

  if (t_lin < GSUM_BLOCKS) {
    // ---- gsum: 256 rows over 8 waves (32 rows each), LDS reduce ----------
    const int b = (int)t_lin;
    const int r0 = b * 256;
    float acc[4][4];
#pragma unroll
    for (int q = 0; q < 4; ++q)
#pragma unroll
      for (int e = 0; e < 4; ++e) acc[q][e] = 0.f;
    int cnt[4] = {0, 0, 0, 0};
    const int rw = r0 + wave * 32;
    for (int k = 0; k < 32; ++k) {
      int row = rw + k;
      int g = sf[row];
      ushort4 v = ((const ushort4*)(znb + (size_t)row * DD))[lane];
      float f0 = bf2f(v.x), f1 = bf2f(v.y), f2 = bf2f(v.z), f3 = bf2f(v.w);
#pragma unroll
      for (int q = 0; q < 4; ++q) {
        bool sel = (g == q);
        acc[q][0] += sel ? f0 : 0.f;
        acc[q][1] += sel ? f1 : 0.f;
        acc[q][2] += sel ? f2 : 0.f;
        acc[q][3] += sel ? f3 : 0.f;
        cnt[q] += sel ? 1 : 0;
      }
    }
    float4* lsd = (float4*)&Bs[0][0];  // 32 x 64 float4 = 32 KB
    int* lcnt = (int*)&As[0][0];       // 32 ints
#pragma unroll
    for (int q = 0; q < 4; ++q) {
      float4 t;
      t.x = acc[q][0]; t.y = acc[q][1]; t.z = acc[q][2]; t.w = acc[q][3];
      lsd[(wave * 4 + q) * 64 + lane] = t;
    }
    if (lane == 0) {
#pragma unroll
      for (int q = 0; q < 4; ++q) lcnt[wave * 4 + q] = cnt[q];
    }
    __syncthreads();
    if (tid < 256) {
      int g = tid >> 6, l = tid & 63;
      float4 s = {0.f, 0.f, 0.f, 0.f};
#pragma unroll
      for (int w = 0; w < 8; ++w) {
        float4 sv = lsd[(w * 4 + g) * 64 + l];
        s.x += sv.x; s.y += sv.y; s.z += sv.z; s.w += sv.w;
      }
      ((float4*)(vsum_part + (size_t)(b * 4 + g) * 256))[l] = s;
      if (tid < 4) {
        int ci = 0;
#pragma unroll
        for (int w = 0; w < 8; ++w) ci += lcnt[w * 4 + tid];
        cnt_part[b * 4 + tid] = ci;
      }
    }
    return;
  }

  // ---- one 128x256 macro tile, 8 waves x (64x64) -------------------------
  unsigned t = t_lin - GSUM_BLOCKS;
  unsigned tr = 0;
  while (t >= 32u - (tr >> 1)) { t -= 32u - (tr >> 1); ++tr; }
  unsigned c = (tr >> 1) + t;
  const size_t rowbase = (size_t)tr * 128;
  const size_t colbase = (size_t)c * 256;

  const int u = lane >> 3;
  const int cp = (lane & 7) ^ u;
  const int ri = 2 * u + (cp >> 2);
  const int kelem = (cp & 3) * 8;
  const int slot = ((((lane & 1) << 2) | (lane >> 4)) ^ ((lane >> 1) & 7));
  const int fragoff = ((lane & 15) >> 1) * 128 + slot * 16;
  const int wrow = wave & 1;       // 64-row half
  const int wcol = wave >> 1;      // 64-col quarter (0..3)

  // wave-uniform symmetry flags at 128x128 sub-block granularity
  const int tch = (int)(2 * c) + (wcol >> 1);     // this wave's 128-col half
  const float fr = (tch >= (int)tr) ? 1.f : 0.f;  // include in row sums
  const float fc = (tch > (int)tr) ? 1.f : 0.f;   // include in col sums

  f32x4 zero = {0.f, 0.f, 0.f, 0.f};
  f32x4 acc[4][4];
#pragma unroll
  for (int i = 0; i < 4; ++i)
#pragma unroll
    for (int j = 0; j < 4; ++j) acc[i][j] = zero;

  // staging: each wave issues 1 A chunk + 2 B chunks (16B/lane each);
  // stage k lands in buffer k%3.
  const unsigned short* gA = znb + (rowbase + wave * 16 + ri) * DD + kelem;
  const unsigned short* gB0 = znb + (colbase + (2 * wave) * 16 + ri) * DD + kelem;
  const unsigned short* gB1 = gB0 + 16 * DD;

  auto stage = [&](int kt, int buf) {
    __builtin_amdgcn_global_load_lds((gvoid_t*)(gA + kt * 32), (lvoid_t*)&As[buf][wave * 512], 16, 0, 0);
    __builtin_amdgcn_global_load_lds((gvoid_t*)(gB0 + kt * 32), (lvoid_t*)&Bs[buf][(2 * wave) * 512], 16, 0, 0);
    __builtin_amdgcn_global_load_lds((gvoid_t*)(gB1 + kt * 32), (lvoid_t*)&Bs[buf][(2 * wave + 1) * 512], 16, 0, 0);
  };

  // counted-vmcnt pipeline, prefetch distance 2 (3 own loads per stage):
  //   top of iter kt: own stage(kt) landed when vmcnt<=3 (stage(kt+1) may
  //   fly); s_barrier => ALL waves' stage(kt) landed. stage(kt+2) then
  //   overwrites buf (kt-1)%3, which every wave finished reading before
  //   this barrier (its kt-1 ds_reads were consumed by its kt-1 MFMAs).
  stage(0, 0);
  stage(1, 1);
#pragma unroll
  for (int kt = 0; kt < 8; ++kt) {
    const int buf = kt % 3;
    if (kt < 7) asm volatile("s_waitcnt vmcnt(3)" ::: "memory");
    else        asm volatile("s_waitcnt vmcnt(0)" ::: "memory");
    __builtin_amdgcn_s_barrier();
    asm volatile("" ::: "memory");  // compiler fence: keep stage() below barrier
    if (kt < 6) stage(kt + 2, (kt + 2) % 3);
    short8 af[4], bfr[4];
#pragma unroll
    for (int mi = 0; mi < 4; ++mi)
      af[mi] = *(const short8*)((const char*)&As[0][0] + buf * 8192 + (wrow * 4 + mi) * 1024 + fragoff);
#pragma unroll
    for (int ni = 0; ni < 4; ++ni)
      bfr[ni] = *(const short8*)((const char*)&Bs[0][0] + buf * 16384 + (wcol * 4 + ni) * 1024 + fragoff);
#pragma unroll
    for (int mi = 0; mi < 4; ++mi)
#pragma unroll
      for (int ni = 0; ni < 4; ++ni)
        acc[mi][ni] = __builtin_amdgcn_mfma_f32_16x16x32_bf16(af[mi], bfr[ni], acc[mi][ni], 0, 0, 0);
  }

  // epilogue: e = exp(2S); row/col sums; combine in LDS; atomics.
  // As[0] (buf 0) is safe scratch: its last reads (kt=6) completed before
  // the kt=7 barrier. C layout: col=lane&15, row=(lane>>4)*4+reg.
  float rsum[4][4];
  float csum[4];
#pragma unroll
  for (int mi = 0; mi < 4; ++mi)
#pragma unroll
    for (int r = 0; r < 4; ++r) rsum[mi][r] = 0.f;
#pragma unroll
  for (int ni = 0; ni < 4; ++ni) csum[ni] = 0.f;
#pragma unroll
  for (int mi = 0; mi < 4; ++mi)
#pragma unroll
    for (int ni = 0; ni < 4; ++ni)
#pragma unroll
      for (int r = 0; r < 4; ++r) {
        float e = __expf(2.0f * acc[mi][ni][r]);
        rsum[mi][r] += e;
        csum[ni] += e;
      }
#pragma unroll
  for (int m = 1; m < 16; m <<= 1)
#pragma unroll
    for (int mi = 0; mi < 4; ++mi)
#pragma unroll
      for (int r = 0; r < 4; ++r) rsum[mi][r] += __shfl_xor(rsum[mi][r], m);
#pragma unroll
  for (int m = 16; m < 64; m <<= 1)
#pragma unroll
    for (int ni = 0; ni < 4; ++ni) csum[ni] += __shfl_xor(csum[ni], m);

  float* Lr = (float*)&As[0][0];  // [4][128] indexed by wcol (2 KB)
  float* Lc = Lr + 512;           // [2][256] indexed by wrow (2 KB)
  if ((lane & 15) == 0) {
    int h = lane >> 4;
#pragma unroll
    for (int mi = 0; mi < 4; ++mi)
#pragma unroll
      for (int r = 0; r < 4; ++r)
        Lr[wcol * 128 + wrow * 64 + mi * 16 + h * 4 + r] = rsum[mi][r] * fr;
  }
  if (lane < 16) {
#pragma unroll
    for (int ni = 0; ni < 4; ++ni)
      Lc[wrow * 256 + wcol * 64 + ni * 16 + lane] = csum[ni] * fc;
  }
  __syncthreads();
  if (tid < 256) {
    float v = Lc[tid] + Lc[256 + tid];
    if (v != 0.f) unsafeAtomicAdd(&den[colbase + tid], v);
  } else if (tid < 384) {
    int r = tid - 256;
    unsafeAtomicAdd(&den[rowbase + r], Lr[r] + Lr[128 + r] + Lr[256 + r] + Lr[384 + r]);
  }
}

// ---------------- kernel C: tail (1 block x 1024) -------------------------
__global__ __launch_bounds__(1024) void tail_kernel(const float* __restrict__ wsf,
                                                    const float* __restrict__ vsum_part,
                                                    const int* __restrict__ cnt_part,
                                                    const float* __restrict__ ppos,
                                                    float* __restrict__ out) {
  __shared__ float sred[48];
  const float* den = wsf;
  const int tid = threadIdx.x;
  const int lane = tid & 63, wave = tid >> 6;  // 16 waves

  const float e2 = __expf(2.0f);
  float ls = 0.f;
#pragma unroll
  for (int k = 0; k < 8; ++k) ls += __logf(den[k * 1024 + tid] - e2);
#pragma unroll
  for (int m = 32; m >= 1; m >>= 1) ls += __shfl_xor(ls, m);
  if (lane == 0) sred[wave] = ls;

  float pp = ppos[tid];
#pragma unroll
  for (int m = 32; m >= 1; m >>= 1) pp += __shfl_xor(pp, m);
  if (lane == 0) sred[16 + wave] = pp;

  // group col-sums: thread t -> g = t>>8, col = t&255 (g wave-uniform)
  {
    int g = tid >> 8, col = tid & 255;
    float v = 0.f;
#pragma unroll
    for (int b = 0; b < 16; ++b) v += vsum_part[(size_t)(b * 4 + g) * 256 + col];
    float gp = v * v;
#pragma unroll
    for (int m = 32; m >= 1; m >>= 1) gp += __shfl_xor(gp, m);
    if (lane == 0) sred[32 + wave] = gp;  // wave w -> group w>>2
  }
  __syncthreads();
  if (tid == 0) {
    float lsum = 0.f, psum = 0.f;
#pragma unroll
    for (int w = 0; w < 16; ++w) { lsum += sred[w]; psum += sred[16 + w]; }
    float contrastive = (lsum - 4.0f * psum) / (float)TWOB;
    float fsum = 0.f;
    int uniq = 0;
#pragma unroll
    for (int q = 0; q < 4; ++q) {
      int ci = 0;
#pragma unroll
      for (int b = 0; b < 16; ++b) ci += cnt_part[b * 4 + q];
      float gsq = sred[32 + q * 4] + sred[33 + q * 4] + sred[34 + q * 4] + sred[35 + q * 4];
      float cf = (float)ci;
      if (ci > 0) uniq++;
      if (ci > 1) fsum += gsq / (cf * (cf - 1.0f));
    }
    out[0] = contrastive + 0.1f * (fsum / (uniq > 0 ? (float)uniq : 1.0f));
  }
}

extern "C" void kernel_launch(void* const* d_in, const int* in_sizes, int n_in,
                              void* d_out, int out_size, void* d_ws, size_t ws_size,
                              hipStream_t stream) {
  const float* zi = (const float*)d_in[0];
  const float* zj = (const float*)d_in[1];
  const int* sf = (const int*)d_in[2];
  float* out = (float*)d_out;
  char* ws = (char*)d_ws;
  float* wsf = (float*)ws;                              // den
  unsigned short* znb = (unsigned short*)(ws + 65536);  // 8192x256 bf16 (4MB)
  float* vsum_part = (float*)(ws + 4259840);            // 16x4x256 f32
  int* cnt_part = (int*)(ws + 4276224);                 // 16x4 int
  float* ppos = (float*)(ws + 4276480);                 // 1024 f32

  hipLaunchKernelGGL(norm_kernel, dim3(1024), dim3(256), 0, stream, zi, zj, wsf, ppos, znb);
  hipLaunchKernelGGL(den_kernel, dim3(64, 17), dim3(512), 0, stream,
                     sf, wsf, znb, vsum_part, cnt_part);
  hipLaunchKernelGGL(tail_kernel, dim3(1), dim3(1024), 0, stream,
                     wsf, vsum_part, cnt_part, ppos, out);
}